// Round 14
// baseline (126.524 us; speedup 1.0000x reference)
//
#include <hip/hip_runtime.h>
#include <hip/hip_bf16.h>
#include <hip/hip_fp8.h>

// Problem constants (fixed by reference): N=4096, D=256, T=0.5, EPS=1e-8
#define PN   4096
#define PN2  8192
#define PD   256                       // bytes per fp8 zn row == K
#define TILE 256
#define NBLK (PN2 / TILE)              // 32 tile-blocks per dim
#define NTRI (NBLK * (NBLK + 1) / 2)   // 528 upper-tri blocks
#define SGRID 256                      // persistent simsum blocks (1/CU)

typedef __attribute__((ext_vector_type(4))) float f32x4;
typedef const __attribute__((address_space(1))) void* gas_ptr;
typedef __attribute__((address_space(3))) void* las_ptr;

__device__ __forceinline__ void tri_decode(int idx, int& bi, int& bj) {
  bj = (int)((sqrtf(8.0f * (float)idx + 1.0f) - 1.0f) * 0.5f);
  while ((bj + 1) * (bj + 2) / 2 <= idx) ++bj;
  while (bj * (bj + 1) / 2 > idx) --bj;
  bi = idx - bj * (bj + 1) / 2;
}

// ---------------------------------------------------------------------------
// Kernel 1: pair-wise normalize (R5/R7-proven, unchanged). One WAVE per pair
// (r, r+N): fp32 norms + dot -> exact fp32 positives; zn rows as OCP e4m3.
// ---------------------------------------------------------------------------
__global__ __launch_bounds__(256) void normalize_kernel(
    const float* __restrict__ zi, const float* __restrict__ zj,
    unsigned char* __restrict__ zn8, float* __restrict__ pos,
    float* __restrict__ wlws, unsigned* __restrict__ ticket) {
  const int wave = threadIdx.x >> 6;
  const int lane = threadIdx.x & 63;
  const int r = blockIdx.x * 4 + wave;           // pair id 0..4095
  float4 a = *(const float4*)(zi + (size_t)r * PD + lane * 4);
  float4 b = *(const float4*)(zj + (size_t)r * PD + lane * 4);
  float si = a.x * a.x + a.y * a.y + a.z * a.z + a.w * a.w;
  float sj = b.x * b.x + b.y * b.y + b.z * b.z + b.w * b.w;
  float d  = a.x * b.x + a.y * b.y + a.z * b.z + a.w * b.w;
  #pragma unroll
  for (int off = 32; off >= 1; off >>= 1) {
    si += __shfl_xor(si, off, 64);
    sj += __shfl_xor(sj, off, 64);
    d  += __shfl_xor(d,  off, 64);
  }
  float ni = fmaxf(sqrtf(si), 1e-8f);
  float nj = fmaxf(sqrtf(sj), 1e-8f);
  if (lane == 0) {
    float p = d / (ni * nj);
    pos[r] = p;
    pos[r + PN] = p;
  }
  float ia = 1.0f / ni, ib = 1.0f / nj;
  union { unsigned u; unsigned char c[4]; } pa, pb;
  pa.c[0] = __hip_cvt_float_to_fp8(a.x * ia, __HIP_SATFINITE, __HIP_E4M3);
  pa.c[1] = __hip_cvt_float_to_fp8(a.y * ia, __HIP_SATFINITE, __HIP_E4M3);
  pa.c[2] = __hip_cvt_float_to_fp8(a.z * ia, __HIP_SATFINITE, __HIP_E4M3);
  pa.c[3] = __hip_cvt_float_to_fp8(a.w * ia, __HIP_SATFINITE, __HIP_E4M3);
  pb.c[0] = __hip_cvt_float_to_fp8(b.x * ib, __HIP_SATFINITE, __HIP_E4M3);
  pb.c[1] = __hip_cvt_float_to_fp8(b.y * ib, __HIP_SATFINITE, __HIP_E4M3);
  pb.c[2] = __hip_cvt_float_to_fp8(b.z * ib, __HIP_SATFINITE, __HIP_E4M3);
  pb.c[3] = __hip_cvt_float_to_fp8(b.w * ib, __HIP_SATFINITE, __HIP_E4M3);
  *(unsigned*)(zn8 + (size_t)r * PD + lane * 4) = pa.u;
  *(unsigned*)(zn8 + (size_t)(r + PN) * PD + lane * 4) = pb.u;
  if (blockIdx.x == 0 && threadIdx.x == 0) {
    wlws[0] = 0.0f; wlws[1] = 0.0f; *ticket = 0u;
  }
}

// ---------------------------------------------------------------------------
// Kernel 2: sim = zn @ zn^T fp8, upper-tri 256x256 whole-tile-in-LDS tiles,
// persistent blocks + B-reuse (R9 schedule), 16 waves (1024 thr), wave-grid
// 4Mx4N, per-wave 64x64 output (acc[4][4] = 64 VGPR).
// R13 RESUBMIT (R13 failed "container failed twice" with no kernel-side
// mechanism in the diff -> treat as infra flake). Only change vs R13:
// __launch_bounds__(1024, 2) instead of (1024, 4) in case the aggressive
// bound itself was the trigger. NOTE the physical constraint is unchanged:
// a 1024-thread block = 16 waves on 4 SIMDs -> 4 waves/SIMD resident ->
// hardware requires <=128 VGPR regardless of the hint, so the anti-spill
// pressure R11 lacked is still present; (1024,2) just gives the allocator a
// valid non-extreme target. Theory unchanged from R12/R13: 4 waves/SIMD
// cover the ds_read->MFMA lgkmcnt chains (R10: dominant compute stall).
// ---------------------------------------------------------------------------
__global__ __launch_bounds__(1024, 2) void simsum_kernel(
    const unsigned char* __restrict__ zn8, float* __restrict__ rowpart) {
  __shared__ char As[TILE * PD];        // 64 KiB
  __shared__ char Bs[TILE * PD];        // 64 KiB
  __shared__ float rowacc[TILE];
  __shared__ float colacc[TILE];

  const int tid  = threadIdx.x;
  const int wave = tid >> 6;           // 0..15
  const int lane = tid & 63;
  const int quad = lane >> 4;
  const int c16  = lane & 15;
  const int waveRow = (wave >> 2) * 64;    // 0,64,128,192
  const int waveCol = (wave & 3) * 64;     // 0,64,128,192

  const int vb = ((int)blockIdx.x & 7) * 32 + ((int)blockIdx.x >> 3);
  int idx = (vb * 33) >> 4;                 // = vb*NTRI/SGRID
  const int idxEnd = ((vb + 1) * 33) >> 4;
  int bi, bj;
  tri_decode(idx, bi, bj);
  int curBj = -1;                           // bj currently resident in Bs

  for (; idx < idxEnd; ++idx) {
    const bool diagBlk = (bi == bj);
    const bool stageB  = (!diagBlk) && (bj != curBj);
    const int rowBase = bi * TILE;
    const int colBase = bj * TILE;

    if (tid < TILE) { rowacc[tid] = 0.0f; colacc[tid] = 0.0f; }

    // stage whole A panel (waves 0-7) and B panel iff bj changed (waves 8-15):
    // 64 (+64) 1KiB issues; LDS granule c16 of row rr holds source granule
    // c16 ^ (rr&15) (rule #21 both-sides swizzle).
    #pragma unroll
    for (int p = 0; p < 8; ++p) {
      int issue = (wave & 7) * 8 + p;      // 0..63 within panel, wave-uniform
      int rr = issue * 4 + quad;           // tile row 0..255
      int gs = c16 ^ (rr & 15);            // source granule for LDS slot c16
      if (wave < 8) {
        const unsigned char* ga = zn8 + (size_t)(rowBase + rr) * PD + gs * 16;
        __builtin_amdgcn_global_load_lds((gas_ptr)ga, (las_ptr)(As + issue * 1024), 16, 0, 0);
      } else if (stageB) {
        const unsigned char* gb = zn8 + (size_t)(colBase + rr) * PD + gs * 16;
        __builtin_amdgcn_global_load_lds((gas_ptr)gb, (las_ptr)(Bs + issue * 1024), 16, 0, 0);
      }
    }
    if (stageB) curBj = bj;
    __syncthreads();   // the ONLY stage barrier per tile (vmcnt(0) drain)

    const char* BsEff = diagBlk ? As : Bs;

    f32x4 acc[4][4];
    #pragma unroll
    for (int i = 0; i < 4; ++i)
      #pragma unroll
      for (int j = 0; j < 4; ++j)
        acc[i][j] = (f32x4){0.f, 0.f, 0.f, 0.f};

    #pragma unroll
    for (int ki = 0; ki < 8; ++ki) {       // 8 x k=32 fp8 MFMA steps, no sync
      // lane's 8 fp8: k = ki*32 + quad*8 + j -> granule G = ki*2 + (quad>>1),
      // half h8; fragment rows satisfy r&15 == c16, so the swizzled offset is
      // row-independent (verified absmax=0 in R11/R12):
      const int off = (((ki * 2 + (quad >> 1)) ^ c16) << 4) + (quad & 1) * 8;
      long b[4];
      #pragma unroll
      for (int ni = 0; ni < 4; ++ni) {
        int r = waveCol + ni * 16 + c16;   // B "row" of zn = sim column n
        b[ni] = *(const long*)(BsEff + r * 256 + off);
      }
      #pragma unroll
      for (int mi = 0; mi < 4; ++mi) {
        int r = waveRow + mi * 16 + c16;   // A row: m = lane&15
        long a = *(const long*)(As + r * 256 + off);
        #pragma unroll
        for (int ni = 0; ni < 4; ++ni)
          acc[mi][ni] = __builtin_amdgcn_mfma_f32_16x16x32_fp8_fp8(a, b[ni], acc[mi][ni], 0, 0, 0);
      }
    }

    // Epilogue (ablation-proven ~free). C/D: col=lane&15, row=quad*4+reg.
    float colsum[4] = {0.f, 0.f, 0.f, 0.f};
    #pragma unroll
    for (int mi = 0; mi < 4; ++mi) {
      int lrow = waveRow + mi * 16 + quad * 4;
      float rs[4] = {0.f, 0.f, 0.f, 0.f};
      #pragma unroll
      for (int ni = 0; ni < 4; ++ni) {
        int gcol = colBase + waveCol + ni * 16 + c16;
        #pragma unroll
        for (int tt = 0; tt < 4; ++tt) {
          int grow = rowBase + lrow + tt;
          float e = __expf(2.0f * acc[mi][ni][tt]);   // exp(sim/T), T=0.5
          if (diagBlk && gcol == grow) e = 0.0f;      // mask diagonal
          rs[tt] += e;
          colsum[ni] += e;
        }
      }
      #pragma unroll
      for (int tt = 0; tt < 4; ++tt) {
        #pragma unroll
        for (int off = 1; off <= 8; off <<= 1) rs[tt] += __shfl_xor(rs[tt], off, 64);
      }
      if (c16 == 0) {
        #pragma unroll
        for (int tt = 0; tt < 4; ++tt) atomicAdd(&rowacc[lrow + tt], rs[tt]);
      }
    }
    if (!diagBlk) {   // column contributions = mirrored rows (symmetry)
      #pragma unroll
      for (int ni = 0; ni < 4; ++ni) {
        float cs = colsum[ni];
        cs += __shfl_xor(cs, 16, 64);
        cs += __shfl_xor(cs, 32, 64);
        if (quad == 0) atomicAdd(&colacc[waveCol + ni * 16 + c16], cs);
      }
    }

    __syncthreads();                // all LDS accumulation done
    if (tid < TILE) {               // plain stores, unique writers:
      rowpart[(size_t)bj * PN2 + rowBase + tid] = rowacc[tid];
      if (!diagBlk)
        rowpart[(size_t)bi * PN2 + colBase + tid] = colacc[tid];
    }
    __syncthreads();                // As/rowacc reusable next tile

    ++bi;                           // next column-major idx
    if (bi > bj) { ++bj; bi = 0; }
  }
}

// ---------------------------------------------------------------------------
// Kernel 3: finalize (R7-proven, unchanged).
// ---------------------------------------------------------------------------
__global__ __launch_bounds__(256) void finalize_kernel(
    const float* __restrict__ rowpart, const float* __restrict__ pos,
    const float* __restrict__ w, float* __restrict__ wlws,
    unsigned* __restrict__ ticket, float* __restrict__ out) {
  const int tid = threadIdx.x;
  const int r = blockIdx.x * 256 + tid;
  float s = 0.0f;
  #pragma unroll
  for (int x = 0; x < NBLK; ++x) s += rowpart[(size_t)x * PN2 + r];
  float li = logf(s) - 2.0f * pos[r];
  float wi = w[r & (PN - 1)];
  float wl = wi * li, ws = wi;
  #pragma unroll
  for (int off = 32; off >= 1; off >>= 1) {
    wl += __shfl_xor(wl, off, 64);
    ws += __shfl_xor(ws, off, 64);
  }
  __shared__ float pl[4], pw[4];
  const int lane = tid & 63, wv = tid >> 6;
  if (lane == 0) { pl[wv] = wl; pw[wv] = ws; }
  __syncthreads();
  if (tid == 0) {
    atomicAdd(&wlws[0], pl[0] + pl[1] + pl[2] + pl[3]);
    atomicAdd(&wlws[1], pw[0] + pw[1] + pw[2] + pw[3]);
    __threadfence();
    if (atomicAdd(ticket, 1u) == 31) {      // last of 32 blocks
      float a = atomicAdd(&wlws[0], 0.0f);  // coherent re-read
      float b = atomicAdd(&wlws[1], 0.0f);
      out[0] = a / b;
    }
  }
}

// ---------------------------------------------------------------------------
extern "C" void kernel_launch(void* const* d_in, const int* in_sizes, int n_in,
                              void* d_out, int out_size, void* d_ws, size_t ws_size,
                              hipStream_t stream) {
  const float* zi = (const float*)d_in[0];
  const float* zj = (const float*)d_in[1];
  const float* w  = (const float*)d_in[2];
  float* out = (float*)d_out;

  // Workspace: zn8 u8[8192*256]=2MiB | rowpart f32[32][8192]=1MiB |
  //            pos f32[8192] | wlws f32[2] | ticket u32
  unsigned char* zn8 = (unsigned char*)d_ws;
  float* rowpart = (float*)((char*)d_ws + (size_t)PN2 * PD);
  float* pos     = rowpart + (size_t)NBLK * PN2;
  float* wlws    = pos + PN2;
  unsigned* ticket = (unsigned*)(wlws + 2);

  normalize_kernel<<<PN / 4, 256, 0, stream>>>(zi, zj, zn8, pos, wlws, ticket);
  simsum_kernel<<<SGRID, 1024, 0, stream>>>(zn8, rowpart);
  finalize_kernel<<<32, 256, 0, stream>>>(rowpart, pos, w, wlws, ticket, out);
}

// Round 15
// 123.760 us; speedup vs baseline: 1.0223x; 1.0223x over previous
//
#include <hip/hip_runtime.h>
#include <hip/hip_bf16.h>
#include <hip/hip_fp8.h>

// Problem constants (fixed by reference): N=4096, D=256, T=0.5, EPS=1e-8
#define PN   4096
#define PN2  8192
#define PD   256                       // bytes per fp8 zn row == K
#define TILE 256
#define NBLK (PN2 / TILE)              // 32 tile-blocks per dim
#define NTRI (NBLK * (NBLK + 1) / 2)   // 528 upper-tri blocks
#define SGRID 256                      // persistent simsum blocks (1/CU)

typedef __attribute__((ext_vector_type(4))) float f32x4;
typedef const __attribute__((address_space(1))) void* gas_ptr;
typedef __attribute__((address_space(3))) void* las_ptr;

__device__ __forceinline__ void tri_decode(int idx, int& bi, int& bj) {
  bj = (int)((sqrtf(8.0f * (float)idx + 1.0f) - 1.0f) * 0.5f);
  while ((bj + 1) * (bj + 2) / 2 <= idx) ++bj;
  while (bj * (bj + 1) / 2 > idx) --bj;
  bi = idx - bj * (bj + 1) / 2;
}

// ---------------------------------------------------------------------------
// Kernel 1: pair-wise normalize (R5/R7-proven, unchanged). One WAVE per pair
// (r, r+N): fp32 norms + dot -> exact fp32 positives; zn rows as OCP e4m3.
// ---------------------------------------------------------------------------
__global__ __launch_bounds__(256) void normalize_kernel(
    const float* __restrict__ zi, const float* __restrict__ zj,
    unsigned char* __restrict__ zn8, float* __restrict__ pos,
    float* __restrict__ wlws, unsigned* __restrict__ ticket) {
  const int wave = threadIdx.x >> 6;
  const int lane = threadIdx.x & 63;
  const int r = blockIdx.x * 4 + wave;           // pair id 0..4095
  float4 a = *(const float4*)(zi + (size_t)r * PD + lane * 4);
  float4 b = *(const float4*)(zj + (size_t)r * PD + lane * 4);
  float si = a.x * a.x + a.y * a.y + a.z * a.z + a.w * a.w;
  float sj = b.x * b.x + b.y * b.y + b.z * b.z + b.w * b.w;
  float d  = a.x * b.x + a.y * b.y + a.z * b.z + a.w * b.w;
  #pragma unroll
  for (int off = 32; off >= 1; off >>= 1) {
    si += __shfl_xor(si, off, 64);
    sj += __shfl_xor(sj, off, 64);
    d  += __shfl_xor(d,  off, 64);
  }
  float ni = fmaxf(sqrtf(si), 1e-8f);
  float nj = fmaxf(sqrtf(sj), 1e-8f);
  if (lane == 0) {
    float p = d / (ni * nj);
    pos[r] = p;
    pos[r + PN] = p;
  }
  float ia = 1.0f / ni, ib = 1.0f / nj;
  union { unsigned u; unsigned char c[4]; } pa, pb;
  pa.c[0] = __hip_cvt_float_to_fp8(a.x * ia, __HIP_SATFINITE, __HIP_E4M3);
  pa.c[1] = __hip_cvt_float_to_fp8(a.y * ia, __HIP_SATFINITE, __HIP_E4M3);
  pa.c[2] = __hip_cvt_float_to_fp8(a.z * ia, __HIP_SATFINITE, __HIP_E4M3);
  pa.c[3] = __hip_cvt_float_to_fp8(a.w * ia, __HIP_SATFINITE, __HIP_E4M3);
  pb.c[0] = __hip_cvt_float_to_fp8(b.x * ib, __HIP_SATFINITE, __HIP_E4M3);
  pb.c[1] = __hip_cvt_float_to_fp8(b.y * ib, __HIP_SATFINITE, __HIP_E4M3);
  pb.c[2] = __hip_cvt_float_to_fp8(b.z * ib, __HIP_SATFINITE, __HIP_E4M3);
  pb.c[3] = __hip_cvt_float_to_fp8(b.w * ib, __HIP_SATFINITE, __HIP_E4M3);
  *(unsigned*)(zn8 + (size_t)r * PD + lane * 4) = pa.u;
  *(unsigned*)(zn8 + (size_t)(r + PN) * PD + lane * 4) = pb.u;
  if (blockIdx.x == 0 && threadIdx.x == 0) {
    wlws[0] = 0.0f; wlws[1] = 0.0f; *ticket = 0u;
  }
}

// ---------------------------------------------------------------------------
// Kernel 2: sim = zn @ zn^T fp8, upper-tri 256x256 whole-tile-in-LDS tiles,
// persistent blocks + B-reuse (R9 schedule), 16 waves (1024 thr), wave-grid
// 4Mx4N, per-wave 64x64 output (acc[4][4] = 64 VGPR).
// THE SPILL FIX: amdgpu_waves_per_eu(4,4) pins the allocator's occupancy
// target to exactly 4 waves/EU -> 128-VGPR budget. R11 (bounds 1024,1) and
// R14 (1024,2) both let the allocator target 8 waves/EU -> 64 VGPR -> acc
// SPILLED (VGPR_Count=64, WRITE_SIZE=43MB scratch, simsum 60us). The 130KiB
// LDS already caps residency at 1 block/CU = 4 waves/EU, so (4,4) costs no
// occupancy and removes the spill. Theory (R10): 4 waves/SIMD cover the
// ds_read->MFMA lgkmcnt chains that dominate the compute phase at 2/SIMD.
// ---------------------------------------------------------------------------
__global__ __attribute__((amdgpu_waves_per_eu(4, 4))) __launch_bounds__(1024)
void simsum_kernel(
    const unsigned char* __restrict__ zn8, float* __restrict__ rowpart) {
  __shared__ char As[TILE * PD];        // 64 KiB
  __shared__ char Bs[TILE * PD];        // 64 KiB
  __shared__ float rowacc[TILE];
  __shared__ float colacc[TILE];

  const int tid  = threadIdx.x;
  const int wave = tid >> 6;           // 0..15
  const int lane = tid & 63;
  const int quad = lane >> 4;
  const int c16  = lane & 15;
  const int waveRow = (wave >> 2) * 64;    // 0,64,128,192
  const int waveCol = (wave & 3) * 64;     // 0,64,128,192

  const int vb = ((int)blockIdx.x & 7) * 32 + ((int)blockIdx.x >> 3);
  int idx = (vb * 33) >> 4;                 // = vb*NTRI/SGRID
  const int idxEnd = ((vb + 1) * 33) >> 4;
  int bi, bj;
  tri_decode(idx, bi, bj);
  int curBj = -1;                           // bj currently resident in Bs

  for (; idx < idxEnd; ++idx) {
    const bool diagBlk = (bi == bj);
    const bool stageB  = (!diagBlk) && (bj != curBj);
    const int rowBase = bi * TILE;
    const int colBase = bj * TILE;

    if (tid < TILE) { rowacc[tid] = 0.0f; colacc[tid] = 0.0f; }

    // stage whole A panel (waves 0-7) and B panel iff bj changed (waves 8-15):
    // 64 (+64) 1KiB issues; LDS granule c16 of row rr holds source granule
    // c16 ^ (rr&15) (rule #21 both-sides swizzle).
    #pragma unroll
    for (int p = 0; p < 8; ++p) {
      int issue = (wave & 7) * 8 + p;      // 0..63 within panel, wave-uniform
      int rr = issue * 4 + quad;           // tile row 0..255
      int gs = c16 ^ (rr & 15);            // source granule for LDS slot c16
      if (wave < 8) {
        const unsigned char* ga = zn8 + (size_t)(rowBase + rr) * PD + gs * 16;
        __builtin_amdgcn_global_load_lds((gas_ptr)ga, (las_ptr)(As + issue * 1024), 16, 0, 0);
      } else if (stageB) {
        const unsigned char* gb = zn8 + (size_t)(colBase + rr) * PD + gs * 16;
        __builtin_amdgcn_global_load_lds((gas_ptr)gb, (las_ptr)(Bs + issue * 1024), 16, 0, 0);
      }
    }
    if (stageB) curBj = bj;
    __syncthreads();   // the ONLY stage barrier per tile (vmcnt(0) drain)

    const char* BsEff = diagBlk ? As : Bs;

    f32x4 acc[4][4];
    #pragma unroll
    for (int i = 0; i < 4; ++i)
      #pragma unroll
      for (int j = 0; j < 4; ++j)
        acc[i][j] = (f32x4){0.f, 0.f, 0.f, 0.f};

    #pragma unroll
    for (int ki = 0; ki < 8; ++ki) {       // 8 x k=32 fp8 MFMA steps, no sync
      // lane's 8 fp8: k = ki*32 + quad*8 + j -> granule G = ki*2 + (quad>>1),
      // half h8; fragment rows satisfy r&15 == c16, so the swizzled offset is
      // row-independent (verified absmax=0 in R11/R12/R14):
      const int off = (((ki * 2 + (quad >> 1)) ^ c16) << 4) + (quad & 1) * 8;
      long b[4];
      #pragma unroll
      for (int ni = 0; ni < 4; ++ni) {
        int r = waveCol + ni * 16 + c16;   // B "row" of zn = sim column n
        b[ni] = *(const long*)(BsEff + r * 256 + off);
      }
      #pragma unroll
      for (int mi = 0; mi < 4; ++mi) {
        int r = waveRow + mi * 16 + c16;   // A row: m = lane&15
        long a = *(const long*)(As + r * 256 + off);
        #pragma unroll
        for (int ni = 0; ni < 4; ++ni)
          acc[mi][ni] = __builtin_amdgcn_mfma_f32_16x16x32_fp8_fp8(a, b[ni], acc[mi][ni], 0, 0, 0);
      }
    }

    // Epilogue (ablation-proven ~free). C/D: col=lane&15, row=quad*4+reg.
    float colsum[4] = {0.f, 0.f, 0.f, 0.f};
    #pragma unroll
    for (int mi = 0; mi < 4; ++mi) {
      int lrow = waveRow + mi * 16 + quad * 4;
      float rs[4] = {0.f, 0.f, 0.f, 0.f};
      #pragma unroll
      for (int ni = 0; ni < 4; ++ni) {
        int gcol = colBase + waveCol + ni * 16 + c16;
        #pragma unroll
        for (int tt = 0; tt < 4; ++tt) {
          int grow = rowBase + lrow + tt;
          float e = __expf(2.0f * acc[mi][ni][tt]);   // exp(sim/T), T=0.5
          if (diagBlk && gcol == grow) e = 0.0f;      // mask diagonal
          rs[tt] += e;
          colsum[ni] += e;
        }
      }
      #pragma unroll
      for (int tt = 0; tt < 4; ++tt) {
        #pragma unroll
        for (int off = 1; off <= 8; off <<= 1) rs[tt] += __shfl_xor(rs[tt], off, 64);
      }
      if (c16 == 0) {
        #pragma unroll
        for (int tt = 0; tt < 4; ++tt) atomicAdd(&rowacc[lrow + tt], rs[tt]);
      }
    }
    if (!diagBlk) {   // column contributions = mirrored rows (symmetry)
      #pragma unroll
      for (int ni = 0; ni < 4; ++ni) {
        float cs = colsum[ni];
        cs += __shfl_xor(cs, 16, 64);
        cs += __shfl_xor(cs, 32, 64);
        if (quad == 0) atomicAdd(&colacc[waveCol + ni * 16 + c16], cs);
      }
    }

    __syncthreads();                // all LDS accumulation done
    if (tid < TILE) {               // plain stores, unique writers:
      rowpart[(size_t)bj * PN2 + rowBase + tid] = rowacc[tid];
      if (!diagBlk)
        rowpart[(size_t)bi * PN2 + colBase + tid] = colacc[tid];
    }
    __syncthreads();                // As/rowacc reusable next tile

    ++bi;                           // next column-major idx
    if (bi > bj) { ++bj; bi = 0; }
  }
}

// ---------------------------------------------------------------------------
// Kernel 3: finalize (R7-proven, unchanged).
// ---------------------------------------------------------------------------
__global__ __launch_bounds__(256) void finalize_kernel(
    const float* __restrict__ rowpart, const float* __restrict__ pos,
    const float* __restrict__ w, float* __restrict__ wlws,
    unsigned* __restrict__ ticket, float* __restrict__ out) {
  const int tid = threadIdx.x;
  const int r = blockIdx.x * 256 + tid;
  float s = 0.0f;
  #pragma unroll
  for (int x = 0; x < NBLK; ++x) s += rowpart[(size_t)x * PN2 + r];
  float li = logf(s) - 2.0f * pos[r];
  float wi = w[r & (PN - 1)];
  float wl = wi * li, ws = wi;
  #pragma unroll
  for (int off = 32; off >= 1; off >>= 1) {
    wl += __shfl_xor(wl, off, 64);
    ws += __shfl_xor(ws, off, 64);
  }
  __shared__ float pl[4], pw[4];
  const int lane = tid & 63, wv = tid >> 6;
  if (lane == 0) { pl[wv] = wl; pw[wv] = ws; }
  __syncthreads();
  if (tid == 0) {
    atomicAdd(&wlws[0], pl[0] + pl[1] + pl[2] + pl[3]);
    atomicAdd(&wlws[1], pw[0] + pw[1] + pw[2] + pw[3]);
    __threadfence();
    if (atomicAdd(ticket, 1u) == 31) {      // last of 32 blocks
      float a = atomicAdd(&wlws[0], 0.0f);  // coherent re-read
      float b = atomicAdd(&wlws[1], 0.0f);
      out[0] = a / b;
    }
  }
}

// ---------------------------------------------------------------------------
extern "C" void kernel_launch(void* const* d_in, const int* in_sizes, int n_in,
                              void* d_out, int out_size, void* d_ws, size_t ws_size,
                              hipStream_t stream) {
  const float* zi = (const float*)d_in[0];
  const float* zj = (const float*)d_in[1];
  const float* w  = (const float*)d_in[2];
  float* out = (float*)d_out;

  // Workspace: zn8 u8[8192*256]=2MiB | rowpart f32[32][8192]=1MiB |
  //            pos f32[8192] | wlws f32[2] | ticket u32
  unsigned char* zn8 = (unsigned char*)d_ws;
  float* rowpart = (float*)((char*)d_ws + (size_t)PN2 * PD);
  float* pos     = rowpart + (size_t)NBLK * PN2;
  float* wlws    = pos + PN2;
  unsigned* ticket = (unsigned*)(wlws + 2);

  normalize_kernel<<<PN / 4, 256, 0, stream>>>(zi, zj, zn8, pos, wlws, ticket);
  simsum_kernel<<<SGRID, 1024, 0, stream>>>(zn8, rowpart);
  finalize_kernel<<<32, 256, 0, stream>>>(rowpart, pos, w, wlws, ticket, out);
}

// Round 16
// 103.409 us; speedup vs baseline: 1.2235x; 1.1968x over previous
//
#include <hip/hip_runtime.h>
#include <hip/hip_bf16.h>
#include <hip/hip_fp8.h>

// Problem constants (fixed by reference): N=4096, D=256, T=0.5, EPS=1e-8
#define PN   4096
#define PN2  8192
#define PD   256                       // bytes per fp8 zn row == K
#define TILE 256
#define NBLK (PN2 / TILE)              // 32 tile-blocks per dim
#define NTRI (NBLK * (NBLK + 1) / 2)   // 528 upper-tri blocks

typedef __attribute__((ext_vector_type(4))) float f32x4;
typedef const __attribute__((address_space(1))) void* gas_ptr;
typedef __attribute__((address_space(3))) void* las_ptr;

__device__ __forceinline__ void tri_decode(int idx, int& bi, int& bj) {
  bj = (int)((sqrtf(8.0f * (float)idx + 1.0f) - 1.0f) * 0.5f);
  while ((bj + 1) * (bj + 2) / 2 <= idx) ++bj;
  while (bj * (bj + 1) / 2 > idx) --bj;
  bi = idx - bj * (bj + 1) / 2;
}

// ---------------------------------------------------------------------------
// FINAL KERNEL — exact R7 source (best measured: 103.095 us, absmax 0.0).
// Session summary of what mattered (16 rounds):
//  * 2080x 2-barrier K-loop phase stall was the original wall (R6 ablation:
//    stage-only and epilogue both ~free; the stall was structural).
//  * fp8 e4m3 denominator (positives kept exact in fp32) halves footprint;
//    whole 256x256 tile fits LDS -> stage ONCE, ONE barrier, 8 sync-free
//    MFMA k-steps. 108.6 -> 103.1 us.
//  * Closed avenues (measured): staged-byte cuts (neutral x3), global-atomic
//    removal (neutral), >2 waves/SIMD (allocator spills acc at any 1024-thr
//    bound variant: VGPR=64 + 43MB scratch x3), cooperative fusion (harness
//    tripwire), 2-blocks/CU at 128^2 (DMA concurrency loss).
//  * Residual budget: ~43us harness fill (untouchable) + ~35us simsum
//    (DMA-latency + LDS-latency at 2 waves/SIMD) + ~20us small kernels/gaps.
// ---------------------------------------------------------------------------

// ---------------------------------------------------------------------------
// Kernel 1: pair-wise normalize. One WAVE per pair (r, r+N): fp32 norms+dot
// -> exact fp32 positives; writes both rows of zn as OCP e4m3 (2 MiB).
// ---------------------------------------------------------------------------
__global__ __launch_bounds__(256) void normalize_kernel(
    const float* __restrict__ zi, const float* __restrict__ zj,
    unsigned char* __restrict__ zn8, float* __restrict__ pos,
    float* __restrict__ wlws, unsigned* __restrict__ ticket) {
  const int wave = threadIdx.x >> 6;
  const int lane = threadIdx.x & 63;
  const int r = blockIdx.x * 4 + wave;           // pair id 0..4095
  float4 a = *(const float4*)(zi + (size_t)r * PD + lane * 4);
  float4 b = *(const float4*)(zj + (size_t)r * PD + lane * 4);
  float si = a.x * a.x + a.y * a.y + a.z * a.z + a.w * a.w;
  float sj = b.x * b.x + b.y * b.y + b.z * b.z + b.w * b.w;
  float d  = a.x * b.x + a.y * b.y + a.z * b.z + a.w * b.w;
  #pragma unroll
  for (int off = 32; off >= 1; off >>= 1) {
    si += __shfl_xor(si, off, 64);
    sj += __shfl_xor(sj, off, 64);
    d  += __shfl_xor(d,  off, 64);
  }
  float ni = fmaxf(sqrtf(si), 1e-8f);
  float nj = fmaxf(sqrtf(sj), 1e-8f);
  if (lane == 0) {
    float p = d / (ni * nj);
    pos[r] = p;
    pos[r + PN] = p;
  }
  float ia = 1.0f / ni, ib = 1.0f / nj;
  union { unsigned u; unsigned char c[4]; } pa, pb;
  pa.c[0] = __hip_cvt_float_to_fp8(a.x * ia, __HIP_SATFINITE, __HIP_E4M3);
  pa.c[1] = __hip_cvt_float_to_fp8(a.y * ia, __HIP_SATFINITE, __HIP_E4M3);
  pa.c[2] = __hip_cvt_float_to_fp8(a.z * ia, __HIP_SATFINITE, __HIP_E4M3);
  pa.c[3] = __hip_cvt_float_to_fp8(a.w * ia, __HIP_SATFINITE, __HIP_E4M3);
  pb.c[0] = __hip_cvt_float_to_fp8(b.x * ib, __HIP_SATFINITE, __HIP_E4M3);
  pb.c[1] = __hip_cvt_float_to_fp8(b.y * ib, __HIP_SATFINITE, __HIP_E4M3);
  pb.c[2] = __hip_cvt_float_to_fp8(b.z * ib, __HIP_SATFINITE, __HIP_E4M3);
  pb.c[3] = __hip_cvt_float_to_fp8(b.w * ib, __HIP_SATFINITE, __HIP_E4M3);
  *(unsigned*)(zn8 + (size_t)r * PD + lane * 4) = pa.u;
  *(unsigned*)(zn8 + (size_t)(r + PN) * PD + lane * 4) = pb.u;
  if (blockIdx.x == 0 && threadIdx.x == 0) {
    wlws[0] = 0.0f; wlws[1] = 0.0f; *ticket = 0u;
  }
}

// ---------------------------------------------------------------------------
// Kernel 2: sim = zn @ zn^T fp8, upper-tri 256x256 tiles, WHOLE-TILE-IN-LDS:
// stage once (128 x 1KiB DMA) -> ONE barrier -> 8 uninterrupted k-steps
// (256 MFMA/wave) -> free epilogue -> unique-writer partial stores.
// 8 waves (512 thr), wave grid 2M x 4N, per-wave 128x64 output.
// ---------------------------------------------------------------------------
__global__ __launch_bounds__(512, 1) void simsum_kernel(
    const unsigned char* __restrict__ zn8, float* __restrict__ rowpart) {
  __shared__ char As[TILE * PD];        // 64 KiB
  __shared__ char Bs[TILE * PD];        // 64 KiB
  __shared__ float rowacc[TILE];
  __shared__ float colacc[TILE];

  const int tid = threadIdx.x;
  if (tid < TILE) { rowacc[tid] = 0.0f; colacc[tid] = 0.0f; }

  // XCD swizzle (bijective, 528 % 8 == 0)
  const int idx = (int)((blockIdx.x & 7) * (NTRI / 8) + (blockIdx.x >> 3));
  int bi, bj;
  tri_decode(idx, bi, bj);
  const bool diagBlk = (bi == bj);

  const int wave = tid >> 6;           // 0..7
  const int lane = tid & 63;
  const int quad = lane >> 4;
  const int c16  = lane & 15;
  const int rowBase = bi * TILE;
  const int colBase = bj * TILE;
  const int waveRow = (wave >> 2) * 128;   // 0,128
  const int waveCol = (wave & 3) * 64;     // 0,64,128,192

  // ---- stage the WHOLE tile once: 64 issues A (+64 B), 8 (+8) per wave ----
  // LDS granule c16 of row rr holds source granule c16 ^ (rr&15) (rule #21).
  #pragma unroll
  for (int p = 0; p < 8; ++p) {
    int issue = wave * 8 + p;            // 0..63, wave-uniform
    int rr = issue * 4 + quad;           // tile row 0..255
    int gs = c16 ^ (rr & 15);            // source granule for LDS slot c16
    const unsigned char* ga = zn8 + (size_t)(rowBase + rr) * PD + gs * 16;
    __builtin_amdgcn_global_load_lds((gas_ptr)ga, (las_ptr)(As + issue * 1024), 16, 0, 0);
    if (!diagBlk) {
      const unsigned char* gb = zn8 + (size_t)(colBase + rr) * PD + gs * 16;
      __builtin_amdgcn_global_load_lds((gas_ptr)gb, (las_ptr)(Bs + issue * 1024), 16, 0, 0);
    }
  }
  __syncthreads();   // the ONLY stage barrier per tile (vmcnt(0) drain)

  const char* BsEff = diagBlk ? As : Bs;

  f32x4 acc[8][4];
  #pragma unroll
  for (int i = 0; i < 8; ++i)
    #pragma unroll
    for (int j = 0; j < 4; ++j)
      acc[i][j] = (f32x4){0.f, 0.f, 0.f, 0.f};

  #pragma unroll
  for (int ki = 0; ki < 8; ++ki) {       // 8 x k=32 fp8 MFMA steps, no sync
    const int G  = ki * 2 + (quad >> 1); // granule 0..15; half h8
    const int h8 = (quad & 1) * 8;
    long b[4];
    #pragma unroll
    for (int ni = 0; ni < 4; ++ni) {
      int r = waveCol + ni * 16 + c16;   // B "row" of zn = sim column n
      b[ni] = *(const long*)(BsEff + r * 256 + (((G ^ (r & 15)) << 4) + h8));
    }
    #pragma unroll
    for (int mi = 0; mi < 8; ++mi) {
      int r = waveRow + mi * 16 + c16;   // A row: m = lane&15
      long a = *(const long*)(As + r * 256 + (((G ^ (r & 15)) << 4) + h8));
      #pragma unroll
      for (int ni = 0; ni < 4; ++ni)
        acc[mi][ni] = __builtin_amdgcn_mfma_f32_16x16x32_fp8_fp8(a, b[ni], acc[mi][ni], 0, 0, 0);
    }
  }

  // Epilogue (ablation-proven ~free). C/D: col=lane&15, row=quad*4+reg.
  float colsum[4] = {0.f, 0.f, 0.f, 0.f};
  #pragma unroll
  for (int mi = 0; mi < 8; ++mi) {
    int lrow = waveRow + mi * 16 + quad * 4;      // local row 0..255
    float rs[4] = {0.f, 0.f, 0.f, 0.f};
    #pragma unroll
    for (int ni = 0; ni < 4; ++ni) {
      int gcol = colBase + waveCol + ni * 16 + c16;
      #pragma unroll
      for (int tt = 0; tt < 4; ++tt) {
        int grow = rowBase + lrow + tt;
        float e = __expf(2.0f * acc[mi][ni][tt]);   // exp(sim/T), T=0.5
        if (diagBlk && gcol == grow) e = 0.0f;      // mask diagonal
        rs[tt] += e;
        colsum[ni] += e;
      }
    }
    #pragma unroll
    for (int tt = 0; tt < 4; ++tt) {
      #pragma unroll
      for (int off = 1; off <= 8; off <<= 1) rs[tt] += __shfl_xor(rs[tt], off, 64);
    }
    if (c16 == 0) {                                  // LDS atomics: per-CU, cheap
      #pragma unroll
      for (int tt = 0; tt < 4; ++tt) atomicAdd(&rowacc[lrow + tt], rs[tt]);
    }
  }
  if (!diagBlk) {   // column contributions = mirrored rows (symmetry)
    #pragma unroll
    for (int ni = 0; ni < 4; ++ni) {
      float cs = colsum[ni];
      cs += __shfl_xor(cs, 16, 64);
      cs += __shfl_xor(cs, 32, 64);
      if (quad == 0) atomicAdd(&colacc[waveCol + ni * 16 + c16], cs);
    }
  }

  __syncthreads();                // all LDS accumulation done
  if (tid < TILE) {               // plain stores, unique writers:
    rowpart[(size_t)bj * PN2 + rowBase + tid] = rowacc[tid];
    if (!diagBlk)
      rowpart[(size_t)bi * PN2 + colBase + tid] = colacc[tid];
  }
}

// ---------------------------------------------------------------------------
// Kernel 3: rowsum[r] = sum_x rowpart[x][r]; loss_r = log(rowsum)-2*pos;
// out = sum(w*loss)/sum(w). 32 blocks x 256 threads, 1 row/thread.
// ---------------------------------------------------------------------------
__global__ __launch_bounds__(256) void finalize_kernel(
    const float* __restrict__ rowpart, const float* __restrict__ pos,
    const float* __restrict__ w, float* __restrict__ wlws,
    unsigned* __restrict__ ticket, float* __restrict__ out) {
  const int tid = threadIdx.x;
  const int r = blockIdx.x * 256 + tid;
  float s = 0.0f;
  #pragma unroll
  for (int x = 0; x < NBLK; ++x) s += rowpart[(size_t)x * PN2 + r];
  float li = logf(s) - 2.0f * pos[r];
  float wi = w[r & (PN - 1)];
  float wl = wi * li, ws = wi;
  #pragma unroll
  for (int off = 32; off >= 1; off >>= 1) {
    wl += __shfl_xor(wl, off, 64);
    ws += __shfl_xor(ws, off, 64);
  }
  __shared__ float pl[4], pw[4];
  const int lane = tid & 63, wv = tid >> 6;
  if (lane == 0) { pl[wv] = wl; pw[wv] = ws; }
  __syncthreads();
  if (tid == 0) {
    atomicAdd(&wlws[0], pl[0] + pl[1] + pl[2] + pl[3]);
    atomicAdd(&wlws[1], pw[0] + pw[1] + pw[2] + pw[3]);
    __threadfence();
    if (atomicAdd(ticket, 1u) == 31) {      // last of 32 blocks
      float a = atomicAdd(&wlws[0], 0.0f);  // coherent re-read
      float b = atomicAdd(&wlws[1], 0.0f);
      out[0] = a / b;
    }
  }
}

// ---------------------------------------------------------------------------
extern "C" void kernel_launch(void* const* d_in, const int* in_sizes, int n_in,
                              void* d_out, int out_size, void* d_ws, size_t ws_size,
                              hipStream_t stream) {
  const float* zi = (const float*)d_in[0];
  const float* zj = (const float*)d_in[1];
  const float* w  = (const float*)d_in[2];
  float* out = (float*)d_out;

  // Workspace: zn8 u8[8192*256]=2MiB | rowpart f32[32][8192]=1MiB |
  //            pos f32[8192] | wlws f32[2] | ticket u32
  unsigned char* zn8 = (unsigned char*)d_ws;
  float* rowpart = (float*)((char*)d_ws + (size_t)PN2 * PD);
  float* pos     = rowpart + (size_t)NBLK * PN2;
  float* wlws    = pos + PN2;
  unsigned* ticket = (unsigned*)(wlws + 2);

  normalize_kernel<<<PN / 4, 256, 0, stream>>>(zi, zj, zn8, pos, wlws, ticket);
  simsum_kernel<<<NTRI, 512, 0, stream>>>(zn8, rowpart);
  finalize_kernel<<<32, 256, 0, stream>>>(rowpart, pos, w, wlws, ticket, out);
}